// Round 1
// baseline (104.852 us; speedup 1.0000x reference)
//
#include <hip/hip_runtime.h>
#include <stdint.h>

#define NB 16384      // batch
#define NK 64         // neighbors per node
#define NF 128        // feature dim
#define NS 16         // samples per row

// ---------------------------------------------------------------------------
// Bit-exact replicas of XLA:CPU's float32 exp/log (Cephes-derived polynomials
// from llvm_ir_runtime.cc GenerateVF32Exp/GenerateVF32Log; fmuladd -> FMA).
// ---------------------------------------------------------------------------
__device__ __forceinline__ float xla_exp_f32(float x_in) {
#pragma clang fp contract(off)
  const float exp_hi = 88.3762626647950f;
  const float exp_lo = -88.3762626647949f;
  const float log2ef = 1.44269504088896341f;
  const float c1 = 0.693359375f;
  const float c2 = -2.12194440e-4f;
  const float p0 = 1.9875691500E-4f;
  const float p1 = 1.3981999507E-3f;
  const float p2 = 8.3334519073E-3f;
  const float p3 = 4.1665795894E-2f;
  const float p4 = 1.6666665459E-1f;
  const float p5 = 5.0000001201E-1f;

  float x = fminf(fmaxf(x_in, exp_lo), exp_hi);
  float fx = floorf(fmaf(x, log2ef, 0.5f));
  float tmp = c1 * fx;          // exact product (c1 has 11-bit mantissa)
  float z2 = c2 * fx;           // separate mul (Cephes/XLA order), then sub
  x = x - tmp;
  x = x - z2;
  float z = x * x;
  float y = fmaf(x, p0, p1);
  y = fmaf(y, x, p2);
  y = fmaf(y, x, p3);
  y = fmaf(y, x, p4);
  y = fmaf(y, x, p5);
  y = fmaf(y, z, x);
  y = y + 1.0f;
  int n = (int)fx;              // FPToSI, fx integral in [-128,128]
  float two_n = __int_as_float((n + 127) << 23);
  return fmaxf(y * two_n, x_in);
}

__device__ __forceinline__ float xla_log_f32(float x_in) {
#pragma clang fp contract(off)
  const float sqrthf = 0.707106781186547524f;
  const float p0 = 7.0376836292E-2f;
  const float p1 = -1.1514610310E-1f;
  const float p2 = 1.1676998740E-1f;
  const float p3 = -1.2420140846E-1f;
  const float p4 = 1.4249322787E-1f;
  const float p5 = -1.6668057665E-1f;
  const float p6 = 2.0000714765E-1f;
  const float p7 = -2.4999993993E-1f;
  const float p8 = 3.3333331174E-1f;
  const float q1 = -2.12194440e-4f;
  const float q2 = 0.693359375f;

  float t = fmaxf(x_in, __uint_as_float(0x00800000u));  // clamp off denormals
  uint32_t bits = __float_as_uint(t);
  float e = (float)((int)(bits >> 23) - 0x7f) + 1.0f;
  float m = __uint_as_float((bits & 0x007fffffu) | 0x3f000000u);  // [0.5,1)
  bool lt = (m < sqrthf);
  float madd = lt ? m : 0.0f;
  e = e - (lt ? 1.0f : 0.0f);
  m = (m + madd) - 1.0f;        // exact either grouping

  float z = m * m;
  float y = fmaf(m, p0, p1);
  y = fmaf(y, m, p2);
  y = fmaf(y, m, p3);
  y = fmaf(y, m, p4);
  y = fmaf(y, m, p5);
  y = fmaf(y, m, p6);
  y = fmaf(y, m, p7);
  y = fmaf(y, m, p8);
  y = y * m;
  y = y * z;
  y = fmaf(e, q1, y);
  y = y - 0.5f * z;             // 0.5*z exact -> FMA-vs-mul+sub identical
  float r = m + y;
  r = fmaf(e, q2, r);
  return r;
}

// ---------------------------------------------------------------------------
// Threefry-2x32 with key (0, 42) == jax.random.key(42); returns both outputs.
// ---------------------------------------------------------------------------
__device__ __forceinline__ void threefry2x32_k42(uint32_t c0, uint32_t c1,
                                                 uint32_t& o0, uint32_t& o1) {
  const uint32_t k0 = 0u, k1 = 42u;
  const uint32_t k2 = k0 ^ k1 ^ 0x1BD11BDAu;
  uint32_t x0 = c0 + k0, x1 = c1 + k1;
#define TF_R(r) { x0 += x1; x1 = (x1 << (r)) | (x1 >> (32 - (r))); x1 ^= x0; }
  TF_R(13) TF_R(15) TF_R(26) TF_R(6)
  x0 += k1; x1 += k2 + 1u;
  TF_R(17) TF_R(29) TF_R(16) TF_R(24)
  x0 += k2; x1 += k0 + 2u;
  TF_R(13) TF_R(15) TF_R(26) TF_R(6)
  x0 += k0; x1 += k1 + 3u;
  TF_R(17) TF_R(29) TF_R(16) TF_R(24)
  x0 += k1; x1 += k2 + 4u;
  TF_R(13) TF_R(15) TF_R(26) TF_R(6)
  x0 += k2; x1 += k0 + 5u;
#undef TF_R
  o0 = x0; o1 = x1;
}

// jax partitionable threefry, 32-bit path: bits[m] = out0 ^ out1 with counts
// (hi32(m), lo32(m)); here m < 2^24 so hi = 0.
__device__ __forceinline__ uint32_t jax_random_bits32(uint32_t m) {
  uint32_t a, b;
  threefry2x32_k42(0u, m, a, b);
  return a ^ b;
}

__device__ __forceinline__ float gumbel_from_bits(uint32_t bits) {
#pragma clang fp contract(off)
  const float tiny = 1.17549435e-38f;                       // finfo(f32).tiny
  float f = __uint_as_float((bits >> 9) | 0x3f800000u) - 1.0f;   // [0,1)
  float u = fmaxf(tiny, f + tiny);   // floats*(1-tiny)+tiny, (1-tiny)==1.0f
  return -xla_log_f32(-xla_log_f32(u));
}

// ---------------------------------------------------------------------------
// One block (1 wave, 64 lanes) per batch row b; lane k owns neighbor k.
// ---------------------------------------------------------------------------
__global__ void __launch_bounds__(64)
dns_kernel(const int* __restrict__ ids, const float* __restrict__ features,
           const int* __restrict__ adj, int* __restrict__ out) {
#pragma clang fp contract(off)
  __shared__ __align__(16) float fc[NF];
  __shared__ float esh[NK];
  __shared__ float zsh[NS][NK + 1];   // +1 pad: conflict-free row scans
  __shared__ int nsh[NK];
  __shared__ float ssum;

  const int b = blockIdx.x;
  const int k = threadIdx.x;
  const int center = ids[b];

  if (k < NF / 4) {
    ((float4*)fc)[k] = ((const float4*)(features + (size_t)center * NF))[k];
  }
  const int nid = adj[(size_t)center * NK + k];
  nsh[k] = nid;
  __syncthreads();

  // distance^2: strictly sequential f32 adds, no FMA (matches XLA reduce)
  const float4* nf4 = (const float4*)(features + (size_t)nid * NF);
  float acc = 0.0f;
#pragma unroll
  for (int j = 0; j < NF / 4; ++j) {
    float4 v = nf4[j];
    float d0 = fc[4 * j + 0] - v.x; acc = acc + d0 * d0;
    float d1 = fc[4 * j + 1] - v.y; acc = acc + d1 * d1;
    float d2 = fc[4 * j + 2] - v.z; acc = acc + d2 * d2;
    float d3 = fc[4 * j + 3] - v.w; acc = acc + d3 * d3;
  }
  float dist = sqrtf(acc);            // IEEE correctly rounded (matches CPU)
  float ev = xla_exp_f32(-dist);
  esh[k] = ev;
  __syncthreads();
  if (k == 0) {                       // sequential 64-term sum (XLA order)
    float s = 0.0f;
    for (int i = 0; i < NK; ++i) s = s + esh[i];
    ssum = s;
  }
  __syncthreads();
  const float logit = xla_log_f32(ev / ssum);  // divide correctly rounded

  // gumbel noise shape (16, 16384, 64): flat m = s*NB*NK + b*NK + k
#pragma unroll
  for (int s = 0; s < NS; ++s) {
    uint32_t m = (uint32_t)((s * NB + b) * NK + k);
    zsh[s][k] = gumbel_from_bits(jax_random_bits32(m)) + logit;
  }
  __syncthreads();

  // argmax over k (first index on tie, matching jnp.argmax), then gather adj
  if (k < NS) {
    float best = zsh[k][0];
    int bi = 0;
#pragma unroll 1
    for (int i = 1; i < NK; ++i) {
      float v = zsh[k][i];
      if (v > best) { best = v; bi = i; }
    }
    out[b * NS + k] = nsh[bi];
  }
}

extern "C" void kernel_launch(void* const* d_in, const int* in_sizes, int n_in,
                              void* d_out, int out_size, void* d_ws, size_t ws_size,
                              hipStream_t stream) {
  // inputs: ids(int32)[16384], num_samples(1), features(f32)[100000*128],
  //         batch_size(1), adj_info(int32)[100000*64]
  const int* ids = (const int*)d_in[0];
  const float* features = (const float*)d_in[2];
  const int* adj = (const int*)d_in[4];
  int* out = (int*)d_out;
  (void)in_sizes; (void)n_in; (void)out_size; (void)d_ws; (void)ws_size;

  dns_kernel<<<dim3(NB), dim3(NK), 0, stream>>>(ids, features, adj, out);
}

// Round 4
// 104.792 us; speedup vs baseline: 1.0006x; 1.0006x over previous
//
#include <hip/hip_runtime.h>
#include <stdint.h>

#define NB 16384      // batch
#define NK 64         // neighbors per node
#define NF 128        // feature dim
#define NS 16         // samples per row
#define RPB 4         // rows (waves) per block

// ---------------------------------------------------------------------------
// Bit-exact replicas of XLA:CPU's float32 exp/log (Cephes-derived polynomials
// from llvm_ir_runtime.cc GenerateVF32Exp/GenerateVF32Log; fmuladd -> FMA).
// DO NOT TOUCH: verified absmax == 0 vs JAX reference in R1.
// ---------------------------------------------------------------------------
__device__ __forceinline__ float xla_exp_f32(float x_in) {
#pragma clang fp contract(off)
  const float exp_hi = 88.3762626647950f;
  const float exp_lo = -88.3762626647949f;
  const float log2ef = 1.44269504088896341f;
  const float c1 = 0.693359375f;
  const float c2 = -2.12194440e-4f;
  const float p0 = 1.9875691500E-4f;
  const float p1 = 1.3981999507E-3f;
  const float p2 = 8.3334519073E-3f;
  const float p3 = 4.1665795894E-2f;
  const float p4 = 1.6666665459E-1f;
  const float p5 = 5.0000001201E-1f;

  float x = fminf(fmaxf(x_in, exp_lo), exp_hi);
  float fx = floorf(fmaf(x, log2ef, 0.5f));
  float tmp = c1 * fx;
  float z2 = c2 * fx;
  x = x - tmp;
  x = x - z2;
  float z = x * x;
  float y = fmaf(x, p0, p1);
  y = fmaf(y, x, p2);
  y = fmaf(y, x, p3);
  y = fmaf(y, x, p4);
  y = fmaf(y, x, p5);
  y = fmaf(y, z, x);
  y = y + 1.0f;
  int n = (int)fx;
  float two_n = __int_as_float((n + 127) << 23);
  return fmaxf(y * two_n, x_in);
}

__device__ __forceinline__ float xla_log_f32(float x_in) {
#pragma clang fp contract(off)
  const float sqrthf = 0.707106781186547524f;
  const float p0 = 7.0376836292E-2f;
  const float p1 = -1.1514610310E-1f;
  const float p2 = 1.1676998740E-1f;
  const float p3 = -1.2420140846E-1f;
  const float p4 = 1.4249322787E-1f;
  const float p5 = -1.6668057665E-1f;
  const float p6 = 2.0000714765E-1f;
  const float p7 = -2.4999993993E-1f;
  const float p8 = 3.3333331174E-1f;
  const float q1 = -2.12194440e-4f;
  const float q2 = 0.693359375f;

  float t = fmaxf(x_in, __uint_as_float(0x00800000u));
  uint32_t bits = __float_as_uint(t);
  float e = (float)((int)(bits >> 23) - 0x7f) + 1.0f;
  float m = __uint_as_float((bits & 0x007fffffu) | 0x3f000000u);
  bool lt = (m < sqrthf);
  float madd = lt ? m : 0.0f;
  e = e - (lt ? 1.0f : 0.0f);
  m = (m + madd) - 1.0f;

  float z = m * m;
  float y = fmaf(m, p0, p1);
  y = fmaf(y, m, p2);
  y = fmaf(y, m, p3);
  y = fmaf(y, m, p4);
  y = fmaf(y, m, p5);
  y = fmaf(y, m, p6);
  y = fmaf(y, m, p7);
  y = fmaf(y, m, p8);
  y = y * m;
  y = y * z;
  y = fmaf(e, q1, y);
  y = y - 0.5f * z;
  float r = m + y;
  r = fmaf(e, q2, r);
  return r;
}

// ---------------------------------------------------------------------------
// Threefry-2x32 with key (0, 42) == jax.random.key(42).
// ---------------------------------------------------------------------------
__device__ __forceinline__ void threefry2x32_k42(uint32_t c0, uint32_t c1,
                                                 uint32_t& o0, uint32_t& o1) {
  const uint32_t k0 = 0u, k1 = 42u;
  const uint32_t k2 = k0 ^ k1 ^ 0x1BD11BDAu;
  uint32_t x0 = c0 + k0, x1 = c1 + k1;
#define TF_R(r) { x0 += x1; x1 = (x1 << (r)) | (x1 >> (32 - (r))); x1 ^= x0; }
  TF_R(13) TF_R(15) TF_R(26) TF_R(6)
  x0 += k1; x1 += k2 + 1u;
  TF_R(17) TF_R(29) TF_R(16) TF_R(24)
  x0 += k2; x1 += k0 + 2u;
  TF_R(13) TF_R(15) TF_R(26) TF_R(6)
  x0 += k0; x1 += k1 + 3u;
  TF_R(17) TF_R(29) TF_R(16) TF_R(24)
  x0 += k1; x1 += k2 + 4u;
  TF_R(13) TF_R(15) TF_R(26) TF_R(6)
  x0 += k2; x1 += k0 + 5u;
#undef TF_R
  o0 = x0; o1 = x1;
}

// jax partitionable threefry, 32-bit path: bits[m] = out0 ^ out1, m < 2^24.
__device__ __forceinline__ uint32_t jax_random_bits32(uint32_t m) {
  uint32_t a, b;
  threefry2x32_k42(0u, m, a, b);
  return a ^ b;
}

__device__ __forceinline__ float gumbel_from_bits(uint32_t bits) {
#pragma clang fp contract(off)
  const float tiny = 1.17549435e-38f;
  float f = __uint_as_float((bits >> 9) | 0x3f800000u) - 1.0f;
  float u = fmaxf(tiny, f + tiny);
  return -xla_log_f32(-xla_log_f32(u));
}

// ---------------------------------------------------------------------------
// R1 kernel body VERBATIM, with only the launch geometry changed: 4 waves per
// 256-thread block, each wave owns one batch row via per-wave LDS slices.
// No dynamic shuffles / butterflies (R2/R3 hang-suspect constructs avoided).
// ---------------------------------------------------------------------------
__global__ void __launch_bounds__(256)
dns_kernel(const int* __restrict__ ids, const float* __restrict__ features,
           const int* __restrict__ adj, int* __restrict__ out) {
#pragma clang fp contract(off)
  __shared__ __align__(16) float fc[RPB][NF];
  __shared__ float esh[RPB][NK];
  __shared__ float zsh[RPB][NS][NK + 1];   // +1 pad: conflict-free row scans
  __shared__ int nsh[RPB][NK];
  __shared__ float ssum[RPB];

  const int wave = threadIdx.x >> 6;
  const int k = threadIdx.x & 63;
  const int b = blockIdx.x * RPB + wave;
  const int center = ids[b];

  if (k < NF / 4) {
    ((float4*)fc[wave])[k] = ((const float4*)(features + (size_t)center * NF))[k];
  }
  const int nid = adj[(size_t)center * NK + k];
  nsh[wave][k] = nid;
  __syncthreads();

  // distance^2: strictly sequential f32 adds, no FMA (matches XLA reduce)
  const float4* nf4 = (const float4*)(features + (size_t)nid * NF);
  float acc = 0.0f;
#pragma unroll
  for (int j = 0; j < NF / 4; ++j) {
    float4 v = nf4[j];
    float d0 = fc[wave][4 * j + 0] - v.x; acc = acc + d0 * d0;
    float d1 = fc[wave][4 * j + 1] - v.y; acc = acc + d1 * d1;
    float d2 = fc[wave][4 * j + 2] - v.z; acc = acc + d2 * d2;
    float d3 = fc[wave][4 * j + 3] - v.w; acc = acc + d3 * d3;
  }
  float dist = sqrtf(acc);            // IEEE correctly rounded (matches CPU)
  float ev = xla_exp_f32(-dist);
  esh[wave][k] = ev;
  __syncthreads();
  if (k == 0) {                       // sequential 64-term sum (XLA order)
    float s = 0.0f;
    for (int i = 0; i < NK; ++i) s = s + esh[wave][i];
    ssum[wave] = s;
  }
  __syncthreads();
  const float logit = xla_log_f32(ev / ssum[wave]);  // divide correctly rounded

  // gumbel noise shape (16, 16384, 64): flat m = s*NB*NK + b*NK + k
#pragma unroll
  for (int s = 0; s < NS; ++s) {
    uint32_t m = (uint32_t)((s * NB + b) * NK + k);
    zsh[wave][s][k] = gumbel_from_bits(jax_random_bits32(m)) + logit;
  }
  __syncthreads();

  // argmax over k (first index on tie, matching jnp.argmax), then gather adj
  if (k < NS) {
    float best = zsh[wave][k][0];
    int bi = 0;
#pragma unroll 1
    for (int i = 1; i < NK; ++i) {
      float v = zsh[wave][k][i];
      if (v > best) { best = v; bi = i; }
    }
    out[b * NS + k] = nsh[wave][bi];
  }
}

extern "C" void kernel_launch(void* const* d_in, const int* in_sizes, int n_in,
                              void* d_out, int out_size, void* d_ws, size_t ws_size,
                              hipStream_t stream) {
  // inputs: ids(int32)[16384], num_samples(1), features(f32)[100000*128],
  //         batch_size(1), adj_info(int32)[100000*64]
  const int* ids = (const int*)d_in[0];
  const float* features = (const float*)d_in[2];
  const int* adj = (const int*)d_in[4];
  int* out = (int*)d_out;
  (void)in_sizes; (void)n_in; (void)out_size; (void)d_ws; (void)ws_size;

  dns_kernel<<<dim3(NB / RPB), dim3(64 * RPB), 0, stream>>>(ids, features, adj, out);
}